// Round 12
// baseline (41.223 us; speedup 1.0000x reference)
//
#include <hip/hip_runtime.h>

// Problem constants
#define NB 64
#define NL 128
#define NQ 128
#define NE 16384

// ws float layout
#define WS_TW    0         // total weight (written by block 0)
#define WS_PART  8         // 512 per-block numerator partials (16B-aligned)

using short8 = __attribute__((ext_vector_type(8))) short;  // 8 bf16
using f32x4  = __attribute__((ext_vector_type(4))) float;

// fp32 -> bf16 bits, round-to-nearest-even
__device__ inline unsigned short f2bf(float f) {
    const unsigned u = __float_as_uint(f);
    return (unsigned short)((u + 0x7fffu + ((u >> 16) & 1u)) >> 16);
}

// ---------------------------------------------------------------------------
// main: 512 blocks x 512 threads, block-local (no inter-block deps).
// block = (b = blk>>3, oct = blk&7 -> i-rows [oct*16, oct*16+16)).
// LDS 43.3 KB -> 2 blocks/CU -> 4 waves/SIMD (2x round 11).
//  1. issue full P_b load; zero W LDS [16][132]; sync
//  2. write P_b -> LDS bf16 [128][136]
//  3. build yb frags from dhw/derr (global, latency hides under 4)
//  4. 2-pack edge scan: tw += w; own-stripe edges -> LDS atomicAdd; sync
//  5. gb frags from P_b LDS columns; wa from W LDS; pa from P_b LDS rows;
//     accG = W*P_b frag, accY = P_b*A frag (8 MFMA); s = <accG,accY>
//  6. block-reduce s -> WS_PART[blk]; blk 0 also reduces tw -> WS_TW.
// ---------------------------------------------------------------------------
__global__ __launch_bounds__(512) void main_kernel(const float* __restrict__ P,
                                                   const float* __restrict__ dhw,
                                                   const float* __restrict__ derr,
                                                   const int*  __restrict__ pairs,
                                                   const float* __restrict__ wts,
                                                   float* __restrict__ ws) {
    __shared__ unsigned short Pbl[128 * 136];  // 34816 B bf16 P_b (padded)
    __shared__ float Wl[16 * 132];             // 8448 B fp32 scatter target
    __shared__ float redS[8], redT[8];

    const int t   = threadIdx.x;
    const int blk = blockIdx.x;                // [0,512)
    const int b   = blk >> 3;
    const int oct = blk & 7;                   // i-rows [oct*16, oct*16+16)
    const float* __restrict__ Pb = P + b * 16384;

    // 1a. issue full P_b load early
    float4 pv[8];
    #pragma unroll
    for (int r = 0; r < 8; ++r) pv[r] = ((const float4*)Pb)[t + 512 * r];

    // 1b. zero Wl (2112 floats)
    for (int idx = t; idx < 16 * 132; idx += 512) Wl[idx] = 0.f;
    __syncthreads();

    // 2. write P_b to LDS as bf16, padded stride 136
    #pragma unroll
    for (int r = 0; r < 8; ++r) {
        const int f   = t + 512 * r;           // ushort4 unit within [128][128]
        const int row = f >> 5, c4 = (f & 31) * 4;
        ushort4 u;
        u.x = f2bf(pv[r].x); u.y = f2bf(pv[r].y);
        u.z = f2bf(pv[r].z); u.w = f2bf(pv[r].w);
        *(ushort4*)&Pbl[row * 136 + c4] = u;
    }

    const int wv   = t >> 6;                   // wave -> q-tile
    const int lane = t & 63;
    const int l15  = lane & 15;
    const int kb   = (lane >> 4) * 8;
    const int ncol = wv * 16 + l15;

    // 3. yb frags (block-invariant; global loads issued before edge scan)
    short8 yb8[4];
    #pragma unroll
    for (int kk = 0; kk < 4; ++kk) {
        const int k0 = kk * 32 + kb;
        short8 y;
        #pragma unroll
        for (int d = 0; d < 8; ++d) {
            const int ai   = (k0 + d) * 128 + ncol;            // A[p][q] idx
            const float hw = dhw[ai], er = derr[ai];
            y[d] = (short)f2bf((hw == 1.0f) ? fmaxf(1.0f - er, 0.f) : 0.f);
        }
        yb8[kk] = y;
    }

    // 4. 2-pack edge scan: total weight + own-stripe LDS scatter
    float tw = 0.f;
    #pragma unroll 4
    for (int r = 0; r < 16; ++r) {
        const int e2 = t + 512 * r;            // 2-edge pack, [0,8192)
        const int4   pr = ((const int4*)pairs)[e2];
        const float2 w2 = ((const float2*)wts)[e2];
        tw += w2.x + w2.y;
        if ((pr.x >> 4) == oct)
            atomicAdd(&Wl[(pr.x & 15) * 132 + pr.y], w2.x);
        if ((pr.z >> 4) == oct)
            atomicAdd(&Wl[(pr.z & 15) * 132 + pr.w], w2.y);
    }
    __syncthreads();

    // 5. gb frags (LDS column gather) + MFMA dot
    short8 gb8[4];
    #pragma unroll
    for (int kk = 0; kk < 4; ++kk) {
        const int k0 = kk * 32 + kb;
        short8 g;
        #pragma unroll
        for (int d = 0; d < 8; ++d)
            g[d] = (short)Pbl[(k0 + d) * 136 + ncol];          // P_b[j][ncol]
        gb8[kk] = g;
    }

    const int mrow = oct * 16 + l15;           // global i row
    f32x4 accG = {0.f, 0.f, 0.f, 0.f};
    f32x4 accY = {0.f, 0.f, 0.f, 0.f};
    #pragma unroll
    for (int kk = 0; kk < 4; ++kk) {
        const int k0 = kk * 32 + kb;
        const float4 w0 = *(const float4*)&Wl[l15 * 132 + k0];
        const float4 w1 = *(const float4*)&Wl[l15 * 132 + k0 + 4];
        short8 wa;
        wa[0] = f2bf(w0.x); wa[1] = f2bf(w0.y);
        wa[2] = f2bf(w0.z); wa[3] = f2bf(w0.w);
        wa[4] = f2bf(w1.x); wa[5] = f2bf(w1.y);
        wa[6] = f2bf(w1.z); wa[7] = f2bf(w1.w);
        const short8 pa = *(const short8*)&Pbl[mrow * 136 + k0];
        accG = __builtin_amdgcn_mfma_f32_16x16x32_bf16(wa, gb8[kk], accG, 0, 0, 0);
        accY = __builtin_amdgcn_mfma_f32_16x16x32_bf16(pa, yb8[kk], accY, 0, 0, 0);
    }
    float s = accG[0] * accY[0] + accG[1] * accY[1]
            + accG[2] * accY[2] + accG[3] * accY[3];

    // 6. block reduce; one plain store per block
    #pragma unroll
    for (int off = 32; off; off >>= 1) s += __shfl_down(s, off, 64);
    if (lane == 0) redS[wv] = s;
    if (blk == 0) {
        #pragma unroll
        for (int off = 32; off; off >>= 1) tw += __shfl_down(tw, off, 64);
        if (lane == 0) redT[wv] = tw;
    }
    __syncthreads();
    if (t == 0) {
        float ss = 0.f;
        #pragma unroll
        for (int k = 0; k < 8; ++k) ss += redS[k];
        ws[WS_PART + blk] = ss;                // distinct slot
        if (blk == 0) {
            float tt = 0.f;
            #pragma unroll
            for (int k = 0; k < 8; ++k) tt += redT[k];
            ws[WS_TW] = tt;
        }
    }
}

// ---------------------------------------------------------------------------
// finalize: 1 block x 512 threads; loss = -(sum(part)/B)/max(tw,1e-8)
// ---------------------------------------------------------------------------
__global__ __launch_bounds__(512) void finalize_kernel(const float* __restrict__ ws,
                                                       float* __restrict__ out) {
    const int t = threadIdx.x, lane = t & 63, wv = t >> 6;
    float n = ws[WS_PART + t];
    #pragma unroll
    for (int off = 32; off; off >>= 1) n += __shfl_down(n, off, 64);
    __shared__ float red[8];
    if (lane == 0) red[wv] = n;
    __syncthreads();
    if (t == 0) {
        float num = 0.f;
        #pragma unroll
        for (int k = 0; k < 8; ++k) num += red[k];
        out[0] = -num / ((float)NB * fmaxf(ws[WS_TW], 1e-8f));
    }
}

extern "C" void kernel_launch(void* const* d_in, const int* in_sizes, int n_in,
                              void* d_out, int out_size, void* d_ws, size_t ws_size,
                              hipStream_t stream) {
    const float* P    = (const float*)d_in[0];
    const float* dhw  = (const float*)d_in[1];
    const float* derr = (const float*)d_in[2];
    const int*   prs  = (const int*)d_in[3];
    const float* wts  = (const float*)d_in[4];
    float* ws  = (float*)d_ws;
    float* out = (float*)d_out;

    main_kernel<<<512, 512, 0, stream>>>(P, dhw, derr, prs, wts, ws);
    finalize_kernel<<<1, 512, 0, stream>>>(ws, out);
}